// Round 17
// baseline (439.793 us; speedup 1.0000x reference)
//
#include <hip/hip_runtime.h>
#include <hip/hip_fp16.h>

#define BATCH   64
#define NCAPS   32
#define NROUTES 2048
#define INDIM   16
#define OUTDIM  32

// ============================================================
// Kernel A v4: single-tile blocks. Grid = cchunk*256 blocks, 8 nodes each.
// Per block: issue W staging (16 KiB global_load_lds, HBM) AND all 8 x
// loads (L3) BEFORE the single barrier -> both latencies overlap; then one
// compute phase and pair-blocked stores. No double-buffer: inter-block
// overlap (4 blocks/CU, 2 generations) hides staging instead.
// Pair-blocked priors layout: pri[cl][pair][b][slot][o] (verified r10/r15).
// (256,2): VGPR cap 256 -> no acc spill (r10 lesson: (256,4) spilled).
// ============================================================
__global__ __launch_bounds__(256, 2) void caps_priors(
    const float* __restrict__ x,
    const float* __restrict__ W,
    unsigned short* __restrict__ pri,
    int c0, int cchunk)
{
    __shared__ float ldsW[4096];      // 16 KiB: 8 nodes x 512 floats

    int bid = blockIdx.x;
    int cl  = bid >> 8;               // 256 blocks per capsule
    int c   = c0 + cl;
    int tg  = bid & 255;              // 8-node tile group
    int t   = threadIdx.x;
    int wv  = t >> 6;
    int l   = t & 63;
    int bl  = l & 31;
    int nodeBase = tg * 8;
    int klocal = wv * 2 + (l >> 5);   // node index within tile (0..7)
    int nl = nodeBase + klocal;       // global node id

    const float* Wt = W + ((size_t)c * NROUTES + nodeBase) * (INDIM * OUTDIM);

    // issue W staging: 16 KiB, 4 rounds x 4 KiB (wave-uniform LDS base,
    // HW adds lane*16B; verified layout r7/r10/r15)
    #pragma unroll
    for (int r = 0; r < 4; ++r) {
        const float* src = Wt + (r * 256 + t) * 4;
        __builtin_amdgcn_global_load_lds(
            (const __attribute__((address_space(1))) void*)src,
            (__attribute__((address_space(3))) void*)&ldsW[(r * 256 + wv * 64) * 4],
            16, 0, 0);
    }

    // issue ALL x loads now -> in flight during the W staging wait
    const float4* xp0 = (const float4*)(x + ((size_t)bl * NROUTES + nl) * INDIM);
    const float4* xp1 = (const float4*)(x + ((size_t)(bl + 32) * NROUTES + nl) * INDIM);
    float4 xq0[4], xq1[4];
    #pragma unroll
    for (int i4 = 0; i4 < 4; ++i4) { xq0[i4] = xp0[i4]; xq1[i4] = xp1[i4]; }

    __syncthreads();   // drains W staging (x loads complete during same wait)

    const float4* wl = (const float4*)&ldsW[klocal * (INDIM * OUTDIM)];

    float acc0[32], acc1[32];
    #pragma unroll
    for (int o = 0; o < 32; ++o) { acc0[o] = 0.f; acc1[o] = 0.f; }

    #pragma unroll
    for (int i4 = 0; i4 < 4; ++i4) {
        const float* xa = (const float*)&xq0[i4];
        const float* xb = (const float*)&xq1[i4];
        #pragma unroll
        for (int ii = 0; ii < 4; ++ii) {
            float a = xa[ii], b = xb[ii];
            #pragma unroll
            for (int o4 = 0; o4 < 8; ++o4) {
                float4 wq = wl[(i4 * 4 + ii) * 8 + o4];
                acc0[o4*4+0] += a * wq.x;  acc1[o4*4+0] += b * wq.x;
                acc0[o4*4+1] += a * wq.y;  acc1[o4*4+1] += b * wq.y;
                acc0[o4*4+2] += a * wq.z;  acc1[o4*4+2] += b * wq.z;
                acc0[o4*4+3] += a * wq.w;  acc1[o4*4+3] += b * wq.w;
            }
        }
    }

    // pair-blocked destination: entry (cl, pair, b) of 64 ushorts,
    // slot (nl&1) selects which 32-ushort half.
    size_t pairIdx = (size_t)cl * (NROUTES / 2) + (nl >> 1);
    size_t slotOff = (size_t)(nl & 1) * OUTDIM;

    uint4 st[4];
    unsigned* sp = (unsigned*)st;
    #pragma unroll
    for (int k = 0; k < 16; ++k) {
        unsigned lo = __half_as_ushort(__float2half_rn(acc0[2*k]));
        unsigned hi = __half_as_ushort(__float2half_rn(acc0[2*k+1]));
        sp[k] = lo | (hi << 16);
    }
    uint4* d0 = (uint4*)(pri + (pairIdx * BATCH + bl) * (2 * OUTDIM) + slotOff);
    d0[0] = st[0]; d0[1] = st[1]; d0[2] = st[2]; d0[3] = st[3];

    #pragma unroll
    for (int k = 0; k < 16; ++k) {
        unsigned lo = __half_as_ushort(__float2half_rn(acc1[2*k]));
        unsigned hi = __half_as_ushort(__float2half_rn(acc1[2*k+1]));
        sp[k] = lo | (hi << 16);
    }
    uint4* d1 = (uint4*)(pri + (pairIdx * BATCH + (bl + 32)) * (2 * OUTDIM) + slotOff);
    d1[0] = st[0]; d1[1] = st[1]; d1[2] = st[2]; d1[3] = st[3];
}

// ============================================================
// Kernel B: routing. One block (1024 thr, 16 waves) per (b, local c).
// Lane l of wave w owns pair w*64+l -> ONE contiguous 128-B read.
// Unchanged (verified r10/r15).
// ============================================================
__global__ __launch_bounds__(1024) void caps_route(
    const unsigned short* __restrict__ pri,
    float* __restrict__ out,
    int c0, int cchunk, int cshift)
{
    int bid = blockIdx.x;
    int b   = bid >> cshift;
    int cl  = bid & (cchunk - 1);
    int c   = c0 + cl;
    int t = threadIdx.x;
    int w = t >> 6;
    int l = t & 63;

    __shared__ float wmax[16];
    __shared__ float wsum[16];
    __shared__ float swave[16][32];
    __shared__ float outArr[32];

    // pair-blocked read: entry (cl, pair = w*64+l, b) -> 128 B contiguous
    size_t pairIdx = (size_t)cl * (NROUTES / 2) + (size_t)w * 64 + l;
    const uint4* pp = (const uint4*)(pri + (pairIdx * BATCH + b) * (2 * OUTDIM));
    uint4 q[8];
    #pragma unroll
    for (int k = 0; k < 8; ++k) q[k] = pp[k];

    float p0[32], p1[32];
    const unsigned* qu = (const unsigned*)q;
    #pragma unroll
    for (int k = 0; k < 16; ++k) {
        __half2 h0 = *(const __half2*)&qu[k];
        __half2 h1 = *(const __half2*)&qu[16 + k];
        float2 f0 = __half22float2(h0);
        float2 f1 = __half22float2(h1);
        p0[2*k]   = f0.x;
        p0[2*k+1] = f0.y;
        p1[2*k]   = f1.x;
        p1[2*k+1] = f1.y;
    }

    float B0 = 0.f, B1 = 0.f;

    for (int it = 0; it < 3; ++it) {
        // per-wave max + sum (stability handled by rescale at combine)
        float m = fmaxf(B0, B1);
        #pragma unroll
        for (int mk = 1; mk < 64; mk <<= 1) m = fmaxf(m, __shfl_xor(m, mk, 64));
        float e0 = __expf(B0 - m);
        float e1 = __expf(B1 - m);
        float sm = e0 + e1;
        #pragma unroll
        for (int mk = 1; mk < 64; mk <<= 1) sm += __shfl_xor(sm, mk, 64);
        if (l == 0) { wmax[w] = m; wsum[w] = sm; }

        // s_loc[o] = e0*p0[o] + e1*p1[o]
        float s[32];
        #pragma unroll
        for (int o = 0; o < 32; ++o) s[o] = e0 * p0[o] + e1 * p1[o];

        // log-split transpose-reduce across 64 lanes (31+1 swizzles)
        #pragma unroll
        for (int step = 0; step < 5; ++step) {
            const int mk = 1 << step;
            const int half = 16 >> step;
            bool bit = (l & mk) != 0;
            #pragma unroll
            for (int k = 0; k < half; ++k) {
                float keep = bit ? s[k + half] : s[k];
                float send = bit ? s[k] : s[k + half];
                s[k] = keep + __shfl_xor(send, mk, 64);
            }
        }
        s[0] += __shfl_xor(s[0], 32, 64);
        int orev = __brev(l & 31) >> 27;   // 5-bit reverse: lane -> o
        if (l < 32) swave[w][orev] = s[0];
        __syncthreads();

        if (t < 32) {
            float M = wmax[0];
            #pragma unroll
            for (int k = 1; k < 16; ++k) M = fmaxf(M, wmax[k]);
            float S = 0.f, sv = 0.f;
            #pragma unroll
            for (int k = 0; k < 16; ++k) {
                float sc = __expf(wmax[k] - M);
                S  += wsum[k] * sc;
                sv += swave[k][t] * sc;
            }
            sv /= S;
            float sq = sv * sv;
            sq += __shfl_xor(sq, 1, 64);
            sq += __shfl_xor(sq, 2, 64);
            sq += __shfl_xor(sq, 4, 64);
            sq += __shfl_xor(sq, 8, 64);
            sq += __shfl_xor(sq, 16, 64);
            float scale = sq / ((1.f + sq) * sqrtf(sq));
            float ov = sv * scale;
            if (it == 2) out[((size_t)b * NCAPS + c) * OUTDIM + t] = ov;
            else         outArr[t] = ov;
        }

        if (it < 2) {
            __syncthreads();
            float o32[32];
            const float4* oa = (const float4*)outArr;
            #pragma unroll
            for (int k = 0; k < 8; ++k) {
                float4 v = oa[k];
                o32[4*k] = v.x; o32[4*k+1] = v.y; o32[4*k+2] = v.z; o32[4*k+3] = v.w;
            }
            float d0a=0,d0b=0,d0c=0,d0d=0, d1a=0,d1b=0,d1c=0,d1d=0;
            #pragma unroll
            for (int k = 0; k < 8; ++k) {
                d0a += p0[4*k]  *o32[4*k];   d0b += p0[4*k+1]*o32[4*k+1];
                d0c += p0[4*k+2]*o32[4*k+2]; d0d += p0[4*k+3]*o32[4*k+3];
                d1a += p1[4*k]  *o32[4*k];   d1b += p1[4*k+1]*o32[4*k+1];
                d1c += p1[4*k+2]*o32[4*k+2]; d1d += p1[4*k+3]*o32[4*k+3];
            }
            B0 += (d0a + d0b) + (d0c + d0d);
            B1 += (d1a + d1b) + (d1c + d1d);
        }
    }
}

// ============================================================
// Fallback (round-1 fused kernel) if ws can't hold even one capsule chunk.
// ============================================================
__global__ __launch_bounds__(1024, 4) void caps_fused(
    const float* __restrict__ x,
    const float* __restrict__ W,
    float* __restrict__ out)
{
    int blk  = blockIdx.x;
    int xcd  = blk & 7;
    int rest = blk >> 3;
    int c = xcd * 4 + (rest >> 6);
    int b = rest & 63;

    int t   = threadIdx.x;
    int w   = t >> 6;
    int l   = t & 63;
    int o   = l & 31;
    int sub = l >> 5;

    __shared__ float Bsh[NROUTES];
    __shared__ float Psh[NROUTES];
    __shared__ float red[1024];
    __shared__ float spart[16][32];
    __shared__ float outArr[32];

    Bsh[t] = 0.0f;
    Bsh[t + 1024] = 0.0f;

    float p[64];
    const int nodeBase = w * 128 + sub;
    const float* Wc = W + (size_t)c * NROUTES * (INDIM * OUTDIM);
    const float* xb = x + (size_t)b * NROUTES * INDIM;

    #pragma unroll 2
    for (int j = 0; j < 64; ++j) {
        int n = nodeBase + 2 * j;
        const float*  wp = Wc + (size_t)n * (INDIM * OUTDIM) + o;
        const float4* xp = (const float4*)(xb + n * INDIM);
        float4 x0 = xp[0], x1 = xp[1], x2 = xp[2], x3 = xp[3];
        float acc = 0.0f;
        acc += x0.x * wp[ 0*32]; acc += x0.y * wp[ 1*32];
        acc += x0.z * wp[ 2*32]; acc += x0.w * wp[ 3*32];
        acc += x1.x * wp[ 4*32]; acc += x1.y * wp[ 5*32];
        acc += x1.z * wp[ 6*32]; acc += x1.w * wp[ 7*32];
        acc += x2.x * wp[ 8*32]; acc += x2.y * wp[ 9*32];
        acc += x2.z * wp[10*32]; acc += x2.w * wp[11*32];
        acc += x3.x * wp[12*32]; acc += x3.y * wp[13*32];
        acc += x3.z * wp[14*32]; acc += x3.w * wp[15*32];
        p[j] = acc;
    }
    __syncthreads();

    for (int it = 0; it < 3; ++it) {
        float m = fmaxf(Bsh[t], Bsh[t + 1024]);
        red[t] = m;
        __syncthreads();
        for (int s = 512; s >= 1; s >>= 1) {
            if (t < s) red[t] = fmaxf(red[t], red[t + s]);
            __syncthreads();
        }
        float M = red[0];
        __syncthreads();

        float e0 = __expf(Bsh[t] - M);
        float e1 = __expf(Bsh[t + 1024] - M);
        Psh[t] = e0;
        Psh[t + 1024] = e1;
        red[t] = e0 + e1;
        __syncthreads();
        for (int s = 512; s >= 1; s >>= 1) {
            if (t < s) red[t] += red[t + s];
            __syncthreads();
        }
        float invS = 1.0f / red[0];
        __syncthreads();

        float local = 0.0f;
        #pragma unroll 8
        for (int j = 0; j < 64; ++j) local += Psh[nodeBase + 2 * j] * p[j];
        local *= invS;
        local += __shfl_xor(local, 32, 64);
        if (l < 32) spart[w][l] = local;
        __syncthreads();

        if (t < 32) {
            float s = 0.0f;
            #pragma unroll
            for (int ww = 0; ww < 16; ++ww) s += spart[ww][t];
            float sq = s * s;
            sq += __shfl_xor(sq, 1, 64);
            sq += __shfl_xor(sq, 2, 64);
            sq += __shfl_xor(sq, 4, 64);
            sq += __shfl_xor(sq, 8, 64);
            sq += __shfl_xor(sq, 16, 64);
            float scale = sq / ((1.0f + sq) * sqrtf(sq));
            outArr[t] = s * scale;
        }
        __syncthreads();

        float outReg = outArr[o];
        if (it < 2) {
            #pragma unroll 8
            for (int j = 0; j < 64; ++j) {
                float a = p[j] * outReg;
                a += __shfl_xor(a, 1, 64);
                a += __shfl_xor(a, 2, 64);
                a += __shfl_xor(a, 4, 64);
                a += __shfl_xor(a, 8, 64);
                a += __shfl_xor(a, 16, 64);
                if ((l & 31) == 0) Bsh[nodeBase + 2 * j] += a;
            }
            __syncthreads();
        }
    }

    if (t < 32) out[((size_t)b * NCAPS + c) * OUTDIM + t] = outArr[t];
}

extern "C" void kernel_launch(void* const* d_in, const int* in_sizes, int n_in,
                              void* d_out, int out_size, void* d_ws, size_t ws_size,
                              hipStream_t stream) {
    const float* x = (const float*)d_in[0];
    const float* W = (const float*)d_in[1];
    float* out = (float*)d_out;

    // Per-capsule workspace slice: 1024 pairs * 64 b * 128 B = 8 MiB.
    const size_t per_c = (size_t)BATCH * NROUTES * OUTDIM * sizeof(unsigned short);

    // Chunk of 8 capsules (64 MiB): priors round-trip stays L3-resident.
    int cchunk = 8;
    while (cchunk >= 1 && (size_t)cchunk * per_c > ws_size) cchunk >>= 1;

    if (cchunk >= 1) {
        const int cshift = __builtin_ctz((unsigned)cchunk);
        for (int c0 = 0; c0 < NCAPS; c0 += cchunk) {
            caps_priors<<<dim3(cchunk * 256), dim3(256), 0, stream>>>(
                x, W, (unsigned short*)d_ws, c0, cchunk);
            caps_route<<<dim3(BATCH * cchunk), dim3(1024), 0, stream>>>(
                (const unsigned short*)d_ws, out, c0, cchunk, cshift);
        }
    } else {
        caps_fused<<<dim3(BATCH * NCAPS), dim3(1024), 0, stream>>>(x, W, out);
    }
}

// Round 20
// 390.030 us; speedup vs baseline: 1.1276x; 1.1276x over previous
//
#include <hip/hip_runtime.h>
#include <hip/hip_fp16.h>

#define BATCH   64
#define NCAPS   32
#define NROUTES 2048
#define INDIM   16
#define OUTDIM  32

// ============================================================
// Kernel A (v3, verified 417.6us @ r15): priors in PAIR-BLOCKED layout
//   pri[cl][pair][b][slot][o], pair = n>>1, slot = n&1.
// Double-buffered 2x16KiB W tiles via global_load_lds; 16 nodes/block.
// (256,2) NOT (256,4): (256,4) made the compiler spill acc0/acc1 to the
// 64-VGPR tier (r10: WRITE +77MB scratch, 109us). Occupancy is 4 blocks/CU
// either way. r17 lesson: single-tile variant (no dbuf, x held in regs
// across barrier) regressed to 110us/dispatch-equiv — keep the dbuf.
// ============================================================
__global__ __launch_bounds__(256, 2) void caps_priors(
    const float* __restrict__ x,
    const float* __restrict__ W,
    unsigned short* __restrict__ pri,
    int c0, int cchunk)
{
    __shared__ float ldsW[2][4096];   // 2 x 16 KiB (8 nodes x 512 floats)

    int bid = blockIdx.x;
    int cl  = bid >> 7;               // 128 blocks per capsule
    int c   = c0 + cl;
    int tg  = bid & 127;              // tile-group: 16 nodes
    int t   = threadIdx.x;
    int wv  = t >> 6;
    int l   = t & 63;
    int bl  = l & 31;
    int nodeBase = tg * 16;

    const float* Wt = W + ((size_t)c * NROUTES + nodeBase) * (INDIM * OUTDIM);

    // stage tile 0 (nodes nodeBase .. nodeBase+7): 16 KiB, 4 rounds x 4 KiB
    #pragma unroll
    for (int r = 0; r < 4; ++r) {
        const float* src = Wt + (r * 256 + t) * 4;
        __builtin_amdgcn_global_load_lds(
            (const __attribute__((address_space(1))) void*)src,
            (__attribute__((address_space(3))) void*)&ldsW[0][(r * 256 + wv * 64) * 4],
            16, 0, 0);
    }
    __syncthreads();

    #pragma unroll
    for (int tt = 0; tt < 2; ++tt) {
        if (tt == 0) {
            // stage tile 1 while computing tile 0 (drained by the barrier below)
            const float* Wt1 = Wt + 8 * (INDIM * OUTDIM);
            #pragma unroll
            for (int r = 0; r < 4; ++r) {
                const float* src = Wt1 + (r * 256 + t) * 4;
                __builtin_amdgcn_global_load_lds(
                    (const __attribute__((address_space(1))) void*)src,
                    (__attribute__((address_space(3))) void*)&ldsW[1][(r * 256 + wv * 64) * 4],
                    16, 0, 0);
            }
        }

        int klocal = wv * 2 + (l >> 5);          // node index within 8-node tile
        int nl = nodeBase + tt * 8 + klocal;     // global node id

        const float4* xp0 = (const float4*)(x + ((size_t)bl * NROUTES + nl) * INDIM);
        const float4* xp1 = (const float4*)(x + ((size_t)(bl + 32) * NROUTES + nl) * INDIM);
        const float4* wl  = (const float4*)&ldsW[tt][klocal * (INDIM * OUTDIM)];

        float acc0[32], acc1[32];
        #pragma unroll
        for (int o = 0; o < 32; ++o) { acc0[o] = 0.f; acc1[o] = 0.f; }

        #pragma unroll
        for (int i4 = 0; i4 < 4; ++i4) {
            float4 xq0 = xp0[i4];
            float4 xq1 = xp1[i4];
            const float* xa = (const float*)&xq0;
            const float* xb = (const float*)&xq1;
            #pragma unroll
            for (int ii = 0; ii < 4; ++ii) {
                float a = xa[ii], b = xb[ii];
                #pragma unroll
                for (int o4 = 0; o4 < 8; ++o4) {
                    float4 wq = wl[(i4 * 4 + ii) * 8 + o4];
                    acc0[o4*4+0] += a * wq.x;  acc1[o4*4+0] += b * wq.x;
                    acc0[o4*4+1] += a * wq.y;  acc1[o4*4+1] += b * wq.y;
                    acc0[o4*4+2] += a * wq.z;  acc1[o4*4+2] += b * wq.z;
                    acc0[o4*4+3] += a * wq.w;  acc1[o4*4+3] += b * wq.w;
                }
            }
        }

        // pair-blocked destination: entry (cl, pair, b) of 64 ushorts,
        // slot (nl&1) selects which 32-ushort half.
        size_t pairIdx = (size_t)cl * (NROUTES / 2) + (nl >> 1);
        size_t slotOff = (size_t)(nl & 1) * OUTDIM;

        uint4 st[4];
        unsigned* sp = (unsigned*)st;
        #pragma unroll
        for (int k = 0; k < 16; ++k) {
            unsigned lo = __half_as_ushort(__float2half_rn(acc0[2*k]));
            unsigned hi = __half_as_ushort(__float2half_rn(acc0[2*k+1]));
            sp[k] = lo | (hi << 16);
        }
        uint4* d0 = (uint4*)(pri + (pairIdx * BATCH + bl) * (2 * OUTDIM) + slotOff);
        d0[0] = st[0]; d0[1] = st[1]; d0[2] = st[2]; d0[3] = st[3];

        #pragma unroll
        for (int k = 0; k < 16; ++k) {
            unsigned lo = __half_as_ushort(__float2half_rn(acc1[2*k]));
            unsigned hi = __half_as_ushort(__float2half_rn(acc1[2*k+1]));
            sp[k] = lo | (hi << 16);
        }
        uint4* d1 = (uint4*)(pri + (pairIdx * BATCH + (bl + 32)) * (2 * OUTDIM) + slotOff);
        d1[0] = st[0]; d1[1] = st[1]; d1[2] = st[2]; d1[3] = st[3];

        if (tt == 0) __syncthreads();   // drains stage(1) after compute(0)
    }
}

// ============================================================
// Kernel B: routing. One block (1024 thr, 16 waves) per (b, local c).
// Lane l of wave w owns pair w*64+l -> ONE contiguous 128-B read.
// Unchanged (verified r10/r15, ~14us/dispatch).
// ============================================================
__global__ __launch_bounds__(1024) void caps_route(
    const unsigned short* __restrict__ pri,
    float* __restrict__ out,
    int c0, int cchunk, int cshift)
{
    int bid = blockIdx.x;
    int b   = bid >> cshift;
    int cl  = bid & (cchunk - 1);
    int c   = c0 + cl;
    int t = threadIdx.x;
    int w = t >> 6;
    int l = t & 63;

    __shared__ float wmax[16];
    __shared__ float wsum[16];
    __shared__ float swave[16][32];
    __shared__ float outArr[32];

    // pair-blocked read: entry (cl, pair = w*64+l, b) -> 128 B contiguous
    size_t pairIdx = (size_t)cl * (NROUTES / 2) + (size_t)w * 64 + l;
    const uint4* pp = (const uint4*)(pri + (pairIdx * BATCH + b) * (2 * OUTDIM));
    uint4 q[8];
    #pragma unroll
    for (int k = 0; k < 8; ++k) q[k] = pp[k];

    float p0[32], p1[32];
    const unsigned* qu = (const unsigned*)q;
    #pragma unroll
    for (int k = 0; k < 16; ++k) {
        __half2 h0 = *(const __half2*)&qu[k];
        __half2 h1 = *(const __half2*)&qu[16 + k];
        float2 f0 = __half22float2(h0);
        float2 f1 = __half22float2(h1);
        p0[2*k]   = f0.x;
        p0[2*k+1] = f0.y;
        p1[2*k]   = f1.x;
        p1[2*k+1] = f1.y;
    }

    float B0 = 0.f, B1 = 0.f;

    for (int it = 0; it < 3; ++it) {
        // per-wave max + sum (stability handled by rescale at combine)
        float m = fmaxf(B0, B1);
        #pragma unroll
        for (int mk = 1; mk < 64; mk <<= 1) m = fmaxf(m, __shfl_xor(m, mk, 64));
        float e0 = __expf(B0 - m);
        float e1 = __expf(B1 - m);
        float sm = e0 + e1;
        #pragma unroll
        for (int mk = 1; mk < 64; mk <<= 1) sm += __shfl_xor(sm, mk, 64);
        if (l == 0) { wmax[w] = m; wsum[w] = sm; }

        // s_loc[o] = e0*p0[o] + e1*p1[o]
        float s[32];
        #pragma unroll
        for (int o = 0; o < 32; ++o) s[o] = e0 * p0[o] + e1 * p1[o];

        // log-split transpose-reduce across 64 lanes (31+1 swizzles)
        #pragma unroll
        for (int step = 0; step < 5; ++step) {
            const int mk = 1 << step;
            const int half = 16 >> step;
            bool bit = (l & mk) != 0;
            #pragma unroll
            for (int k = 0; k < half; ++k) {
                float keep = bit ? s[k + half] : s[k];
                float send = bit ? s[k] : s[k + half];
                s[k] = keep + __shfl_xor(send, mk, 64);
            }
        }
        s[0] += __shfl_xor(s[0], 32, 64);
        int orev = __brev(l & 31) >> 27;   // 5-bit reverse: lane -> o
        if (l < 32) swave[w][orev] = s[0];
        __syncthreads();

        if (t < 32) {
            float M = wmax[0];
            #pragma unroll
            for (int k = 1; k < 16; ++k) M = fmaxf(M, wmax[k]);
            float S = 0.f, sv = 0.f;
            #pragma unroll
            for (int k = 0; k < 16; ++k) {
                float sc = __expf(wmax[k] - M);
                S  += wsum[k] * sc;
                sv += swave[k][t] * sc;
            }
            sv /= S;
            float sq = sv * sv;
            sq += __shfl_xor(sq, 1, 64);
            sq += __shfl_xor(sq, 2, 64);
            sq += __shfl_xor(sq, 4, 64);
            sq += __shfl_xor(sq, 8, 64);
            sq += __shfl_xor(sq, 16, 64);
            float scale = sq / ((1.f + sq) * sqrtf(sq));
            float ov = sv * scale;
            if (it == 2) out[((size_t)b * NCAPS + c) * OUTDIM + t] = ov;
            else         outArr[t] = ov;
        }

        if (it < 2) {
            __syncthreads();
            float o32[32];
            const float4* oa = (const float4*)outArr;
            #pragma unroll
            for (int k = 0; k < 8; ++k) {
                float4 v = oa[k];
                o32[4*k] = v.x; o32[4*k+1] = v.y; o32[4*k+2] = v.z; o32[4*k+3] = v.w;
            }
            float d0a=0,d0b=0,d0c=0,d0d=0, d1a=0,d1b=0,d1c=0,d1d=0;
            #pragma unroll
            for (int k = 0; k < 8; ++k) {
                d0a += p0[4*k]  *o32[4*k];   d0b += p0[4*k+1]*o32[4*k+1];
                d0c += p0[4*k+2]*o32[4*k+2]; d0d += p0[4*k+3]*o32[4*k+3];
                d1a += p1[4*k]  *o32[4*k];   d1b += p1[4*k+1]*o32[4*k+1];
                d1c += p1[4*k+2]*o32[4*k+2]; d1d += p1[4*k+3]*o32[4*k+3];
            }
            B0 += (d0a + d0b) + (d0c + d0d);
            B1 += (d1a + d1b) + (d1c + d1d);
        }
    }
}

// ============================================================
// Fallback (round-1 fused kernel) if ws can't hold even one capsule chunk.
// ============================================================
__global__ __launch_bounds__(1024, 4) void caps_fused(
    const float* __restrict__ x,
    const float* __restrict__ W,
    float* __restrict__ out)
{
    int blk  = blockIdx.x;
    int xcd  = blk & 7;
    int rest = blk >> 3;
    int c = xcd * 4 + (rest >> 6);
    int b = rest & 63;

    int t   = threadIdx.x;
    int w   = t >> 6;
    int l   = t & 63;
    int o   = l & 31;
    int sub = l >> 5;

    __shared__ float Bsh[NROUTES];
    __shared__ float Psh[NROUTES];
    __shared__ float red[1024];
    __shared__ float spart[16][32];
    __shared__ float outArr[32];

    Bsh[t] = 0.0f;
    Bsh[t + 1024] = 0.0f;

    float p[64];
    const int nodeBase = w * 128 + sub;
    const float* Wc = W + (size_t)c * NROUTES * (INDIM * OUTDIM);
    const float* xb = x + (size_t)b * NROUTES * INDIM;

    #pragma unroll 2
    for (int j = 0; j < 64; ++j) {
        int n = nodeBase + 2 * j;
        const float*  wp = Wc + (size_t)n * (INDIM * OUTDIM) + o;
        const float4* xp = (const float4*)(xb + n * INDIM);
        float4 x0 = xp[0], x1 = xp[1], x2 = xp[2], x3 = xp[3];
        float acc = 0.0f;
        acc += x0.x * wp[ 0*32]; acc += x0.y * wp[ 1*32];
        acc += x0.z * wp[ 2*32]; acc += x0.w * wp[ 3*32];
        acc += x1.x * wp[ 4*32]; acc += x1.y * wp[ 5*32];
        acc += x1.z * wp[ 6*32]; acc += x1.w * wp[ 7*32];
        acc += x2.x * wp[ 8*32]; acc += x2.y * wp[ 9*32];
        acc += x2.z * wp[10*32]; acc += x2.w * wp[11*32];
        acc += x3.x * wp[12*32]; acc += x3.y * wp[13*32];
        acc += x3.z * wp[14*32]; acc += x3.w * wp[15*32];
        p[j] = acc;
    }
    __syncthreads();

    for (int it = 0; it < 3; ++it) {
        float m = fmaxf(Bsh[t], Bsh[t + 1024]);
        red[t] = m;
        __syncthreads();
        for (int s = 512; s >= 1; s >>= 1) {
            if (t < s) red[t] = fmaxf(red[t], red[t + s]);
            __syncthreads();
        }
        float M = red[0];
        __syncthreads();

        float e0 = __expf(Bsh[t] - M);
        float e1 = __expf(Bsh[t + 1024] - M);
        Psh[t] = e0;
        Psh[t + 1024] = e1;
        red[t] = e0 + e1;
        __syncthreads();
        for (int s = 512; s >= 1; s >>= 1) {
            if (t < s) red[t] += red[t + s];
            __syncthreads();
        }
        float invS = 1.0f / red[0];
        __syncthreads();

        float local = 0.0f;
        #pragma unroll 8
        for (int j = 0; j < 64; ++j) local += Psh[nodeBase + 2 * j] * p[j];
        local *= invS;
        local += __shfl_xor(local, 32, 64);
        if (l < 32) spart[w][l] = local;
        __syncthreads();

        if (t < 32) {
            float s = 0.0f;
            #pragma unroll
            for (int ww = 0; ww < 16; ++ww) s += spart[ww][t];
            float sq = s * s;
            sq += __shfl_xor(sq, 1, 64);
            sq += __shfl_xor(sq, 2, 64);
            sq += __shfl_xor(sq, 4, 64);
            sq += __shfl_xor(sq, 8, 64);
            sq += __shfl_xor(sq, 16, 64);
            float scale = sq / ((1.0f + sq) * sqrtf(sq));
            outArr[t] = s * scale;
        }
        __syncthreads();

        float outReg = outArr[o];
        if (it < 2) {
            #pragma unroll 8
            for (int j = 0; j < 64; ++j) {
                float a = p[j] * outReg;
                a += __shfl_xor(a, 1, 64);
                a += __shfl_xor(a, 2, 64);
                a += __shfl_xor(a, 4, 64);
                a += __shfl_xor(a, 8, 64);
                a += __shfl_xor(a, 16, 64);
                if ((l & 31) == 0) Bsh[nodeBase + 2 * j] += a;
            }
            __syncthreads();
        }
    }

    if (t < 32) out[((size_t)b * NCAPS + c) * OUTDIM + t] = outArr[t];
}

extern "C" void kernel_launch(void* const* d_in, const int* in_sizes, int n_in,
                              void* d_out, int out_size, void* d_ws, size_t ws_size,
                              hipStream_t stream) {
    const float* x = (const float*)d_in[0];
    const float* W = (const float*)d_in[1];
    float* out = (float*)d_out;

    // Per-capsule workspace slice: 1024 pairs * 64 b * 128 B = 8 MiB.
    const size_t per_c = (size_t)BATCH * NROUTES * OUTDIM * sizeof(unsigned short);

    // Chunk of 16 capsules (128 MiB slice; harness ws is >=512 MiB per the
    // fillBuffer counters). Halves dispatch count vs cchunk=8 -> fewer
    // inter-dispatch gaps; slice still L3-resident (128 MiB < 256 MiB L3).
    int cchunk = 16;
    while (cchunk >= 1 && (size_t)cchunk * per_c > ws_size) cchunk >>= 1;

    if (cchunk >= 1) {
        const int cshift = __builtin_ctz((unsigned)cchunk);
        for (int c0 = 0; c0 < NCAPS; c0 += cchunk) {
            caps_priors<<<dim3(cchunk * 128), dim3(256), 0, stream>>>(
                x, W, (unsigned short*)d_ws, c0, cchunk);
            caps_route<<<dim3(BATCH * cchunk), dim3(1024), 0, stream>>>(
                (const unsigned short*)d_ws, out, c0, cchunk, cshift);
        }
    } else {
        caps_fused<<<dim3(BATCH * NCAPS), dim3(1024), 0, stream>>>(x, W, out);
    }
}